// Round 1
// 329.780 us; speedup vs baseline: 1.0354x; 1.0354x over previous
//
#include <hip/hip_runtime.h>

// B=2,T=4,V=4,H=128,W=128, NQ=64, QDIM=256, IDIM=32, MDIM=16
#define BT     8
#define VHW    (4*128*128)
#define NQn    64
#define QD     256
#define ID     32
#define MD     16
#define CD     48
#define APW    65          // assignment_prob row width (bg + 64 fg)
#define LOCS   128         // locations per entity block
#define PPITCH 52          // pooled LDS pitch (f32): 52*4=208B -> 2-way max on write/read

typedef short bf16x8 __attribute__((ext_vector_type(8)));
typedef float f32x4  __attribute__((ext_vector_type(4)));

// fp32 -> bf16 RNE, independent of __hip_bfloat16 internals
static __device__ __forceinline__ short f2bf(float f) {
    unsigned u = __builtin_bit_cast(unsigned, f);
    unsigned r = (u + 0x7FFFu + ((u >> 16) & 1u)) >> 16;
    return (short)r;
}

// Kernel A: project query_feat -> bf16 table PRE-PACKED in MFMA B-fragment layout:
// qtabB[bt][ntile 0..2][ktile 0..1][lane 0..63][j 0..7], where for 16x16x32 bf16
// B-frag: n = lane&15, k = (lane>>4)*8 + j. Global d = ntile*16+n, q = ktile*32+k.
__global__ __launch_bounds__(256) void qproj_kernel(
    const float* __restrict__ qf,   // [BT*64][256]
    const float* __restrict__ Wi,   // [256][32]
    const float* __restrict__ bi,   // [32]
    const float* __restrict__ Wm,   // [256][16]
    const float* __restrict__ bm,   // [16]
    short* __restrict__ qtabB)      // [BT][3][2][64][8] bf16
{
    int idx = blockIdx.x * 256 + threadIdx.x;   // 8*64*48 = 24576
    int btq = idx / CD;            // bt*64 + q
    int d   = idx - btq * CD;      // 0..47
    int bt  = btq >> 6;
    int q   = btq & 63;
    const float* __restrict__ qrow = qf + btq * QD;
    float a;
    if (d < ID) {
        a = bi[d];
        #pragma unroll 8
        for (int k = 0; k < QD; ++k) a = fmaf(qrow[k], Wi[k*ID + d], a);
    } else {
        int dm = d - ID;
        a = bm[dm];
        #pragma unroll 8
        for (int k = 0; k < QD; ++k) a = fmaf(qrow[k], Wm[k*MD + dm], a);
    }
    int nt = d >> 4, c = d & 15;
    int kt = q >> 5, kk = q & 31;
    int lane = ((kk >> 3) << 4) | c;
    int j    = kk & 7;
    qtabB[((((bt*3 + nt)*2 + kt) << 6) + lane) * 8 + j] = f2bf(a);
}

// Kernel B: per block, 128 locations. Linear raw-f32 ap staging; bf16 convert at
// fragment read; pooled = P @ Q via MFMA (psum via ones column); pooled scaled
// into LDS (aliased over ap buffer); coalesced float4 streaming epilogue.
__global__ __launch_bounds__(256, 4) void entity_kernel(
    const float* __restrict__ ia,     // [BT*VHW][32]
    const float* __restrict__ mc,     // [BT*VHW][16]
    const float* __restrict__ ap,     // [BT*VHW][65]
    const int*   __restrict__ aq,     // [BT*VHW]
    const short* __restrict__ qtabB,  // [BT][3][2][64][8] bf16
    float* __restrict__ out_id,
    float* __restrict__ out_inst,     // [BT*VHW][32]
    float* __restrict__ out_mot)      // [BT*VHW][16]
{
    // raw ap tile [128][65] f32 (33,280 B), later aliased as pooled [128][52] f32
    __shared__ __align__(16) float smem[LOCS * APW];
    __shared__ float psum_s[LOCS];
    __shared__ float scale_s[LOCS];

    const int  t    = threadIdx.x;
    const int  lane = t & 63;
    const int  w    = t >> 6;             // wave id 0..3
    const int  bt   = blockIdx.x >> 9;    // 512 blocks per bt (uniform)
    const long base = (long)blockIdx.x * LOCS;

    // ---- stage ap tile: coalesced float4 global -> linear LDS (no reshuffle) ----
    {
        const float4* __restrict__ src = (const float4*)(ap + base * APW); // 33,280B, 16B aligned
        float4* __restrict__ dst = (float4*)smem;
        #pragma unroll
        for (int k = 0; k < 8; ++k) dst[t + 256 * k] = src[t + 256 * k];
        if (t < (LOCS * APW / 4 - 2048)) dst[2048 + t] = src[2048 + t];    // 2080 f4 total
    }

    // ---- B fragments: coalesced 16B loads from pre-packed table ----
    bf16x8 Bf[3][2];
    {
        const bf16x8* __restrict__ qb = (const bf16x8*)(qtabB + bt * (3*2*64*8));
        #pragma unroll
        for (int nt = 0; nt < 3; ++nt)
            #pragma unroll
            for (int kt = 0; kt < 2; ++kt)
                Bf[nt][kt] = qb[(nt*2 + kt) * 64 + lane];
    }
    bf16x8 Bones;
    {
        short one = ((lane & 15) == 0) ? (short)0x3F80 : (short)0;  // bf16 1.0
        #pragma unroll
        for (int j = 0; j < 8; ++j) Bones[j] = one;
    }

    // ---- prefetch epilogue operands (latency hides under staging + MFMA) ----
    float4 ia_r[4], mc_r[2];
    float  idv = 0.f;
    {
        const float4* __restrict__ ia4 = (const float4*)(ia + base * ID); // 1024 f4
        const float4* __restrict__ mc4 = (const float4*)(mc + base * MD); // 512 f4
        #pragma unroll
        for (int k = 0; k < 4; ++k) ia_r[k] = ia4[t + 256 * k];
        #pragma unroll
        for (int k = 0; k < 2; ++k) mc_r[k] = mc4[t + 256 * k];
        if (t < LOCS) idv = (float)aq[base + t];
    }

    __syncthreads();

    // ---- MFMA: 2 M-tiles x (3 N-tiles + psum) x 2 K-steps ----
    const int c = lane & 15, g = lane >> 4;
    f32x4 acc[2][3];
    f32x4 accP[2];
    #pragma unroll
    for (int m = 0; m < 2; ++m) {
        accP[m] = (f32x4){0.f, 0.f, 0.f, 0.f};
        #pragma unroll
        for (int n = 0; n < 3; ++n) acc[m][n] = (f32x4){0.f, 0.f, 0.f, 0.f};
    }
    #pragma unroll
    for (int kt = 0; kt < 2; ++kt) {
        #pragma unroll
        for (int m = 0; m < 2; ++m) {
            // A-frag: row = w*32 + m*16 + c, k = kt*32 + g*8 + j; ap col = 1+k
            // LDS dword idx = row*65 + 1 + k: 4B aligned; 65 == 1 (mod 32) -> <=2-way bank
            const float* __restrict__ ar = smem + (w*32 + m*16 + c) * APW + 1 + kt*32 + g*8;
            bf16x8 A;
            #pragma unroll
            for (int j = 0; j < 8; ++j) A[j] = f2bf(ar[j]);
            acc[m][0] = __builtin_amdgcn_mfma_f32_16x16x32_bf16(A, Bf[0][kt], acc[m][0], 0, 0, 0);
            acc[m][1] = __builtin_amdgcn_mfma_f32_16x16x32_bf16(A, Bf[1][kt], acc[m][1], 0, 0, 0);
            acc[m][2] = __builtin_amdgcn_mfma_f32_16x16x32_bf16(A, Bf[2][kt], acc[m][2], 0, 0, 0);
            accP[m]   = __builtin_amdgcn_mfma_f32_16x16x32_bf16(A, Bones,     accP[m],   0, 0, 0);
        }
    }

    // ---- psum broadcast: C layout col=lane&15, row=(lane>>4)*4+reg ----
    if (c == 0) {
        #pragma unroll
        for (int m = 0; m < 2; ++m)
            #pragma unroll
            for (int r = 0; r < 4; ++r)
                psum_s[w*32 + m*16 + g*4 + r] = accP[m][r];
    }
    __syncthreads();
    if (t < LOCS)
        scale_s[t] = (1.0f - smem[t * APW]) / fmaxf(psum_s[t], 1e-6f);
    __syncthreads();

    // ---- scaled pooled -> LDS [128][52] (overwrites dead ap region) ----
    #pragma unroll
    for (int m = 0; m < 2; ++m) {
        const int lrow = w*32 + m*16 + g*4;
        #pragma unroll
        for (int r = 0; r < 4; ++r) {
            const float s  = scale_s[lrow + r];
            const int   po = (lrow + r) * PPITCH;
            smem[po + c]      = s * acc[m][0][r];
            smem[po + 16 + c] = s * acc[m][1][r];
            smem[po + 32 + c] = s * acc[m][2][r];
        }
    }
    __syncthreads();

    // ---- streaming epilogue: fully coalesced float4 ----
    float4* __restrict__ oi4 = (float4*)(out_inst + base * ID);
    float4* __restrict__ om4 = (float4*)(out_mot  + base * MD);
    #pragma unroll
    for (int k = 0; k < 4; ++k) {
        int i = t + 256 * k;            // 0..1023
        int loc = i >> 3, d4 = i & 7;
        const float* p = smem + loc * PPITCH + d4 * 4;   // 16B aligned
        float4 v = ia_r[k];
        v.x += p[0]; v.y += p[1]; v.z += p[2]; v.w += p[3];
        oi4[i] = v;
    }
    #pragma unroll
    for (int k = 0; k < 2; ++k) {
        int i = t + 256 * k;            // 0..511
        int loc = i >> 2, d4 = i & 3;
        const float* p = smem + loc * PPITCH + 32 + d4 * 4;
        float4 v = mc_r[k];
        v.x += p[0]; v.y += p[1]; v.z += p[2]; v.w += p[3];
        om4[i] = v;
    }
    if (t < LOCS) out_id[base + t] = idv;
}

extern "C" void kernel_launch(void* const* d_in, const int* in_sizes, int n_in,
                              void* d_out, int out_size, void* d_ws, size_t ws_size,
                              hipStream_t stream) {
    const float* ia = (const float*)d_in[0];
    const float* mc = (const float*)d_in[1];
    const float* qf = (const float*)d_in[2];
    const float* ap = (const float*)d_in[3];
    const int*   aq = (const int*)  d_in[4];
    const float* Wi = (const float*)d_in[5];
    const float* bi = (const float*)d_in[6];
    const float* Wm = (const float*)d_in[7];
    const float* bm = (const float*)d_in[8];

    short* qtabB = (short*)d_ws;                       // 8*3*2*64*8*2 = 49,152 B

    float* out_id   = (float*)d_out;
    float* out_inst = out_id + (long)BT * VHW;
    float* out_mot  = out_inst + (long)BT * VHW * ID;

    qproj_kernel<<<(BT * NQn * CD) / 256, 256, 0, stream>>>(qf, Wi, bi, Wm, bm, qtabB);
    entity_kernel<<<(BT * VHW) / LOCS, 256, 0, stream>>>(ia, mc, ap, aq, qtabB,
                                                         out_id, out_inst, out_mot);
}

// Round 2
// 311.064 us; speedup vs baseline: 1.0977x; 1.0602x over previous
//
#include <hip/hip_runtime.h>

// B=2,T=4,V=4,H=128,W=128, NQ=64, QDIM=256, IDIM=32, MDIM=16
#define BT     8
#define VHW    (4*128*128)
#define NQn    64
#define QD     256
#define ID     32
#define MD     16
#define CD     48
#define APW    65          // assignment_prob row width (bg + 64 fg)

typedef short bf16x8 __attribute__((ext_vector_type(8)));
typedef float f32x4  __attribute__((ext_vector_type(4)));

// fp32 -> bf16 RNE, independent of __hip_bfloat16 internals
static __device__ __forceinline__ short f2bf(float f) {
    unsigned u = __builtin_bit_cast(unsigned, f);
    unsigned r = (u + 0x7FFFu + ((u >> 16) & 1u)) >> 16;
    return (short)r;
}

// Kernel A: project query_feat -> bf16 table PRE-PACKED in MFMA B-fragment layout.
// Grid = BT*NQn = 512 blocks (one per (bt,q) row), 256 threads: 4-way k-split.
// ks = t>>6 (k-chunk 0..3), d = t&63 (output dim, d<48 active).
// B-frag layout: qtabB[bt][nt 0..2][kt 0..1][lane][j]; n=lane&15, k=(lane>>4)*8+j.
__global__ __launch_bounds__(256) void qproj_kernel(
    const float* __restrict__ qf,   // [BT*64][256]
    const float* __restrict__ Wi,   // [256][32]
    const float* __restrict__ bi,   // [32]
    const float* __restrict__ Wm,   // [256][16]
    const float* __restrict__ bm,   // [16]
    short* __restrict__ qtabB)      // [BT][3][2][64][8] bf16
{
    __shared__ float part[4][CD];
    const int btq = blockIdx.x;          // bt*64 + q
    const int bt  = btq >> 6;
    const int q   = btq & 63;
    const int ks  = threadIdx.x >> 6;    // k-chunk
    const int d   = threadIdx.x & 63;

    if (d < CD) {
        const float* __restrict__ qrow = qf + btq * QD + ks * 64;
        float a = 0.f;
        if (d < ID) {
            #pragma unroll 8
            for (int j = 0; j < 64; ++j) a = fmaf(qrow[j], Wi[(ks*64 + j)*ID + d], a);
        } else {
            const int dm = d - ID;
            #pragma unroll 8
            for (int j = 0; j < 64; ++j) a = fmaf(qrow[j], Wm[(ks*64 + j)*MD + dm], a);
        }
        part[ks][d] = a;
    }
    __syncthreads();
    if (ks == 0 && d < CD) {
        float s = (d < ID ? bi[d] : bm[d - ID])
                + part[0][d] + part[1][d] + part[2][d] + part[3][d];
        const int nt = d >> 4, c = d & 15;
        const int kt = q >> 5, kk = q & 31;
        const int lane = ((kk >> 3) << 4) | c;
        const int j    = kk & 7;
        qtabB[((((bt*3 + nt)*2 + kt) << 6) + lane) * 8 + j] = f2bf(s);
    }
}

// Kernel B: barrier-free, LDS-free streaming. Each wave owns 32 rows (2 M-tiles).
// A-fragments read directly from global (per-lane contiguous 8-float runs),
// psum via in-register fp32 reduce + 2 shuffles, scale redistributed via 4
// shuffles, pooled = P @ Q via MFMA, residual-add epilogue in fragment order.
__global__ __launch_bounds__(256) void entity_kernel(
    const float* __restrict__ ia,     // [BT*VHW][32]
    const float* __restrict__ mc,     // [BT*VHW][16]
    const float* __restrict__ ap,     // [BT*VHW][65]
    const int*   __restrict__ aq,     // [BT*VHW]
    const short* __restrict__ qtabB,  // [BT][3][2][64][8] bf16
    float* __restrict__ out_id,
    float* __restrict__ out_inst,     // [BT*VHW][32]
    float* __restrict__ out_mot)      // [BT*VHW][16]
{
    const int t    = threadIdx.x;
    const int lane = t & 63;
    const int w    = t >> 6;              // wave 0..3
    const int c    = lane & 15;           // frag col / A row-within-tile
    const int g    = lane >> 4;           // k-group / C row-group
    const int bt   = blockIdx.x >> 9;     // 512 blocks per bt (uniform)
    const long rb  = (long)blockIdx.x * 128 + w * 32;   // wave's first row

    // ---- B fragments: coalesced 16B loads from pre-packed table (L2-hot) ----
    bf16x8 Bf[3][2];
    {
        const bf16x8* __restrict__ qb = (const bf16x8*)(qtabB + bt * (3*2*64*8));
        #pragma unroll
        for (int nt = 0; nt < 3; ++nt)
            #pragma unroll
            for (int kt = 0; kt < 2; ++kt)
                Bf[nt][kt] = qb[(nt*2 + kt) * 64 + lane];
    }

    // ---- A fragments (raw fp32) + bg, straight from global ----
    // A row = rb + m*16 + c ; k = kt*32 + g*8 + j ; ap col = 1 + k
    float Af[2][2][8];
    float bg[2];
    #pragma unroll
    for (int m = 0; m < 2; ++m) {
        const float* __restrict__ arow = ap + (rb + m*16 + c) * APW;
        bg[m] = arow[0];
        #pragma unroll
        for (int kt = 0; kt < 2; ++kt) {
            const float* __restrict__ ar = arow + 1 + kt*32 + g*8;
            #pragma unroll
            for (int j = 0; j < 8; ++j) Af[m][kt][j] = ar[j];
        }
    }

    // ---- epilogue operands, fragment order (issued early; latency hides) ----
    // C row = rb + m*16 + 4*g + r, col c (+16 for n=1)
    float ia_r[2][2][4], mc_r[2][4];
    #pragma unroll
    for (int m = 0; m < 2; ++m)
        #pragma unroll
        for (int r = 0; r < 4; ++r) {
            const long row = rb + m*16 + 4*g + r;
            ia_r[m][0][r] = ia[row*ID + c];
            ia_r[m][1][r] = ia[row*ID + 16 + c];
            mc_r[m][r]    = mc[row*MD + c];
        }
    float idv = 0.f;
    if (lane < 32) idv = (float)aq[rb + lane];

    // ---- psum (fp32, exact-ish) + scale, all in-register ----
    // row (m*16+c)'s 64 probs live in lanes {c, c+16, c+32, c+48}
    float scale[2][4];
    #pragma unroll
    for (int m = 0; m < 2; ++m) {
        float s = 0.f;
        #pragma unroll
        for (int kt = 0; kt < 2; ++kt)
            #pragma unroll
            for (int j = 0; j < 8; ++j) s += Af[m][kt][j];
        s += __shfl_xor(s, 16);
        s += __shfl_xor(s, 32);
        const float sc = (1.0f - bg[m]) / fmaxf(s, 1e-6f);
        // redistribute to C-fragment rows: row 4g+r comes from lane (4g+r) (c==row, g'==0)
        #pragma unroll
        for (int r = 0; r < 4; ++r) scale[m][r] = __shfl(sc, 4*g + r);
    }

    // ---- pack A to bf16, MFMA ----
    bf16x8 Ab[2][2];
    #pragma unroll
    for (int m = 0; m < 2; ++m)
        #pragma unroll
        for (int kt = 0; kt < 2; ++kt)
            #pragma unroll
            for (int j = 0; j < 8; ++j) Ab[m][kt][j] = f2bf(Af[m][kt][j]);

    f32x4 acc[2][3];
    #pragma unroll
    for (int m = 0; m < 2; ++m)
        #pragma unroll
        for (int n = 0; n < 3; ++n) acc[m][n] = (f32x4){0.f, 0.f, 0.f, 0.f};
    #pragma unroll
    for (int kt = 0; kt < 2; ++kt)
        #pragma unroll
        for (int m = 0; m < 2; ++m) {
            acc[m][0] = __builtin_amdgcn_mfma_f32_16x16x32_bf16(Ab[m][kt], Bf[0][kt], acc[m][0], 0, 0, 0);
            acc[m][1] = __builtin_amdgcn_mfma_f32_16x16x32_bf16(Ab[m][kt], Bf[1][kt], acc[m][1], 0, 0, 0);
            acc[m][2] = __builtin_amdgcn_mfma_f32_16x16x32_bf16(Ab[m][kt], Bf[2][kt], acc[m][2], 0, 0, 0);
        }

    // ---- epilogue: residual add + store in fragment order ----
    #pragma unroll
    for (int m = 0; m < 2; ++m)
        #pragma unroll
        for (int r = 0; r < 4; ++r) {
            const long row = rb + m*16 + 4*g + r;
            const float s = scale[m][r];
            out_inst[row*ID + c]      = ia_r[m][0][r] + s * acc[m][0][r];
            out_inst[row*ID + 16 + c] = ia_r[m][1][r] + s * acc[m][1][r];
            out_mot [row*MD + c]      = mc_r[m][r]    + s * acc[m][2][r];
        }
    if (lane < 32) out_id[rb + lane] = idv;
}

extern "C" void kernel_launch(void* const* d_in, const int* in_sizes, int n_in,
                              void* d_out, int out_size, void* d_ws, size_t ws_size,
                              hipStream_t stream) {
    const float* ia = (const float*)d_in[0];
    const float* mc = (const float*)d_in[1];
    const float* qf = (const float*)d_in[2];
    const float* ap = (const float*)d_in[3];
    const int*   aq = (const int*)  d_in[4];
    const float* Wi = (const float*)d_in[5];
    const float* bi = (const float*)d_in[6];
    const float* Wm = (const float*)d_in[7];
    const float* bm = (const float*)d_in[8];

    short* qtabB = (short*)d_ws;                       // 8*3*2*64*8*2 = 49,152 B

    float* out_id   = (float*)d_out;
    float* out_inst = out_id + (long)BT * VHW;
    float* out_mot  = out_inst + (long)BT * VHW * ID;

    qproj_kernel<<<BT * NQn, 256, 0, stream>>>(qf, Wi, bi, Wm, bm, qtabB);
    entity_kernel<<<(BT * VHW) / 128, 256, 0, stream>>>(ia, mc, ap, aq, qtabB,
                                                        out_id, out_inst, out_mot);
}